// Round 2
// baseline (100.875 us; speedup 1.0000x reference)
//
#include <hip/hip_runtime.h>
#include <math.h>

// Loss_58317065945194: per-sample EMD over C=10 bins, averaged over B samples.
//   diff = p - q               [B, C]
//   cdf  = cumsum(diff, axis=1)
//   per_sample = (mean_c |cdf|^r)^(1/r)
//   out = mean_b per_sample
// Memory-bound: 2 * B*C*4 bytes read, 4 bytes written.
// Single kernel: per-block partials + device-scope flag; last block reduces
// partials in fixed order (deterministic) and writes the scalar.

constexpr int C = 10;
constexpr int BLOCK = 256;
constexpr int NBLOCKS = 2048;  // 256 CUs * 8 blocks/CU

__device__ __forceinline__ float block_reduce_sum(float v) {
    // wave(64) shuffle reduce, then LDS across the 4 waves of a 256 block
    #pragma unroll
    for (int off = 32; off > 0; off >>= 1)
        v += __shfl_down(v, off, 64);
    __shared__ float smem[BLOCK / 64];
    const int lane = threadIdx.x & 63;
    const int wid  = threadIdx.x >> 6;
    if (lane == 0) smem[wid] = v;
    __syncthreads();
    float s = 0.0f;
    if (threadIdx.x == 0) {
        #pragma unroll
        for (int w = 0; w < BLOCK / 64; ++w) s += smem[w];
    }
    return s;  // valid in thread 0 only
}

__global__ __launch_bounds__(BLOCK) void emd_fused(
    const float* __restrict__ p, const float* __restrict__ q,
    const int* __restrict__ rptr, float* __restrict__ partial,
    unsigned int* __restrict__ flag, float* __restrict__ out, int B)
{
    const int tid = blockIdx.x * blockDim.x + threadIdx.x;
    const int nth = gridDim.x * blockDim.x;
    const int r   = rptr[0];
    const int npairs = B >> 1;

    float local = 0.0f;

    if (r == 2) {
        for (int pi = tid; pi < npairs; pi += nth) {
            // 2 samples = 20 floats = 5 float4 per array; byte base pi*80 is 16B-aligned
            const float4* p4 = reinterpret_cast<const float4*>(p) + (size_t)pi * 5;
            const float4* q4 = reinterpret_cast<const float4*>(q) + (size_t)pi * 5;
            float d[2 * C];
            #pragma unroll
            for (int k = 0; k < 5; ++k) {
                float4 a = p4[k];
                float4 b = q4[k];
                d[4*k+0] = a.x - b.x;
                d[4*k+1] = a.y - b.y;
                d[4*k+2] = a.z - b.z;
                d[4*k+3] = a.w - b.w;
            }
            #pragma unroll
            for (int s = 0; s < 2; ++s) {
                float cum = 0.0f, acc = 0.0f;
                #pragma unroll
                for (int c = 0; c < C; ++c) {
                    cum += d[s * C + c];
                    acc += cum * cum;
                }
                local += sqrtf(acc * (1.0f / C));
            }
        }
    } else {
        const float rf = (float)r;
        const float rinv = 1.0f / rf;
        for (int pi = tid; pi < npairs; pi += nth) {
            const float4* p4 = reinterpret_cast<const float4*>(p) + (size_t)pi * 5;
            const float4* q4 = reinterpret_cast<const float4*>(q) + (size_t)pi * 5;
            float d[2 * C];
            #pragma unroll
            for (int k = 0; k < 5; ++k) {
                float4 a = p4[k];
                float4 b = q4[k];
                d[4*k+0] = a.x - b.x;
                d[4*k+1] = a.y - b.y;
                d[4*k+2] = a.z - b.z;
                d[4*k+3] = a.w - b.w;
            }
            #pragma unroll
            for (int s = 0; s < 2; ++s) {
                float cum = 0.0f, acc = 0.0f;
                #pragma unroll
                for (int c = 0; c < C; ++c) {
                    cum += d[s * C + c];
                    acc += powf(fabsf(cum), rf);
                }
                local += powf(acc * (1.0f / C), rinv);
            }
        }
    }

    // tail sample if B is odd (not expected for B=2M, but be correct)
    if ((B & 1) && tid == 0) {
        const size_t base = (size_t)(B - 1) * C;
        float cum = 0.0f, acc = 0.0f;
        for (int c = 0; c < C; ++c) {
            cum += p[base + c] - q[base + c];
            acc += (r == 2) ? cum * cum : powf(fabsf(cum), (float)r);
        }
        local += (r == 2) ? sqrtf(acc * (1.0f / C))
                          : powf(acc * (1.0f / C), 1.0f / (float)r);
    }

    float s = block_reduce_sum(local);

    __shared__ bool is_last;
    if (threadIdx.x == 0) {
        partial[blockIdx.x] = s;
        __threadfence();                         // make partial visible device-wide
        unsigned int old = atomicAdd(flag, 1u);  // device-scope by default on CDNA
        is_last = (old == gridDim.x - 1);
    }
    __syncthreads();

    if (is_last) {
        __threadfence();  // acquire: invalidate L1 so we see all partials
        const volatile float* vp = partial;
        float local2 = 0.0f;
        for (int i = threadIdx.x; i < (int)gridDim.x; i += BLOCK)
            local2 += vp[i];
        float tot = block_reduce_sum(local2);
        if (threadIdx.x == 0) out[0] = tot / (float)B;
    }
}

extern "C" void kernel_launch(void* const* d_in, const int* in_sizes, int n_in,
                              void* d_out, int out_size, void* d_ws, size_t ws_size,
                              hipStream_t stream) {
    const float* p = (const float*)d_in[0];
    const float* q = (const float*)d_in[1];
    const int*   r = (const int*)d_in[2];
    float* out     = (float*)d_out;

    float* partial     = (float*)d_ws;
    unsigned int* flag = (unsigned int*)((char*)d_ws + NBLOCKS * sizeof(float));

    const int B = in_sizes[0] / C;

    int nblocks = NBLOCKS;
    const size_t need = (size_t)NBLOCKS * sizeof(float) + sizeof(unsigned int);
    if (ws_size < need) {
        // fall back to whatever fits (ws is expected to be plenty large)
        nblocks = (int)((ws_size - sizeof(unsigned int)) / sizeof(float));
        if (nblocks < 1) nblocks = 1;
        flag = (unsigned int*)((char*)d_ws + nblocks * sizeof(float));
    }

    hipMemsetAsync(flag, 0, sizeof(unsigned int), stream);
    emd_fused<<<nblocks, BLOCK, 0, stream>>>(p, q, r, partial, flag, out, B);
}

// Round 3
// 47.670 us; speedup vs baseline: 2.1161x; 2.1161x over previous
//
#include <hip/hip_runtime.h>
#include <math.h>

// Loss_58317065945194: per-sample EMD over C=10 bins, averaged over B samples.
//   diff = p - q               [B, C]
//   cdf  = cumsum(diff, axis=1)
//   per_sample = (mean_c |cdf|^r)^(1/r)
//   out = mean_b per_sample
// Memory-bound: 2 * B*C*4 bytes read, 4 bytes written.
//
// Single streaming kernel. Cross-block completion uses AGENT-scope atomics
// only (point-coherent, no buffer_wbl2/buffer_inv cache walks -- the
// __threadfence() version cost +100us from per-block L2 maintenance).
// Last-arriving block sums the 2048 partials in fixed order (deterministic).

constexpr int C = 10;
constexpr int BLOCK = 256;
constexpr int NBLOCKS = 2048;  // 256 CUs * 8 blocks/CU

__device__ __forceinline__ float block_reduce_sum(float v) {
    // wave(64) shuffle reduce, then LDS across the 4 waves of a 256 block
    #pragma unroll
    for (int off = 32; off > 0; off >>= 1)
        v += __shfl_down(v, off, 64);
    __shared__ float smem[BLOCK / 64];
    const int lane = threadIdx.x & 63;
    const int wid  = threadIdx.x >> 6;
    if (lane == 0) smem[wid] = v;
    __syncthreads();
    float s = 0.0f;
    if (threadIdx.x == 0) {
        #pragma unroll
        for (int w = 0; w < BLOCK / 64; ++w) s += smem[w];
    }
    return s;  // valid in thread 0 only
}

__global__ __launch_bounds__(BLOCK) void emd_fused(
    const float* __restrict__ p, const float* __restrict__ q,
    const int* __restrict__ rptr, float* __restrict__ partial,
    unsigned int* __restrict__ flag, float* __restrict__ out, int B)
{
    const int tid = blockIdx.x * blockDim.x + threadIdx.x;
    const int nth = gridDim.x * blockDim.x;
    const int r   = rptr[0];
    const int npairs = B >> 1;

    float local = 0.0f;

    if (r == 2) {
        for (int pi = tid; pi < npairs; pi += nth) {
            // 2 samples = 20 floats = 5 float4 per array; byte base pi*80 is 16B-aligned
            const float4* p4 = reinterpret_cast<const float4*>(p) + (size_t)pi * 5;
            const float4* q4 = reinterpret_cast<const float4*>(q) + (size_t)pi * 5;
            float d[2 * C];
            #pragma unroll
            for (int k = 0; k < 5; ++k) {
                float4 a = p4[k];
                float4 b = q4[k];
                d[4*k+0] = a.x - b.x;
                d[4*k+1] = a.y - b.y;
                d[4*k+2] = a.z - b.z;
                d[4*k+3] = a.w - b.w;
            }
            #pragma unroll
            for (int s = 0; s < 2; ++s) {
                float cum = 0.0f, acc = 0.0f;
                #pragma unroll
                for (int c = 0; c < C; ++c) {
                    cum += d[s * C + c];
                    acc += cum * cum;
                }
                local += sqrtf(acc * (1.0f / C));
            }
        }
    } else {
        const float rf = (float)r;
        const float rinv = 1.0f / rf;
        for (int pi = tid; pi < npairs; pi += nth) {
            const float4* p4 = reinterpret_cast<const float4*>(p) + (size_t)pi * 5;
            const float4* q4 = reinterpret_cast<const float4*>(q) + (size_t)pi * 5;
            float d[2 * C];
            #pragma unroll
            for (int k = 0; k < 5; ++k) {
                float4 a = p4[k];
                float4 b = q4[k];
                d[4*k+0] = a.x - b.x;
                d[4*k+1] = a.y - b.y;
                d[4*k+2] = a.z - b.z;
                d[4*k+3] = a.w - b.w;
            }
            #pragma unroll
            for (int s = 0; s < 2; ++s) {
                float cum = 0.0f, acc = 0.0f;
                #pragma unroll
                for (int c = 0; c < C; ++c) {
                    cum += d[s * C + c];
                    acc += powf(fabsf(cum), rf);
                }
                local += powf(acc * (1.0f / C), rinv);
            }
        }
    }

    // tail sample if B is odd (not expected for B=2M, but be correct)
    if ((B & 1) && tid == 0) {
        const size_t base = (size_t)(B - 1) * C;
        float cum = 0.0f, acc = 0.0f;
        for (int c = 0; c < C; ++c) {
            cum += p[base + c] - q[base + c];
            acc += (r == 2) ? cum * cum : powf(fabsf(cum), (float)r);
        }
        local += (r == 2) ? sqrtf(acc * (1.0f / C))
                          : powf(acc * (1.0f / C), 1.0f / (float)r);
    }

    float s = block_reduce_sum(local);

    __shared__ bool is_last;
    if (threadIdx.x == 0) {
        // Agent-scope atomic store: goes to the device coherence point, so no
        // cache writeback is needed to publish it.
        __hip_atomic_store(&partial[blockIdx.x], s,
                           __ATOMIC_RELAXED, __HIP_MEMORY_SCOPE_AGENT);
        // Ensure the store is acked (device-visible) before signaling arrival.
        asm volatile("s_waitcnt vmcnt(0)" ::: "memory");
        unsigned int old = __hip_atomic_fetch_add(flag, 1u,
                           __ATOMIC_RELAXED, __HIP_MEMORY_SCOPE_AGENT);
        is_last = (old == gridDim.x - 1);
    }
    __syncthreads();   // broadcast is_last; also orders smem reuse below

    if (is_last) {
        // All partials were acked at the coherence point before their flag
        // increments; agent-scope atomic loads bypass stale local caches.
        float local2 = 0.0f;
        for (int i = threadIdx.x; i < (int)gridDim.x; i += BLOCK)
            local2 += __hip_atomic_load(&partial[i],
                         __ATOMIC_RELAXED, __HIP_MEMORY_SCOPE_AGENT);
        float tot = block_reduce_sum(local2);
        if (threadIdx.x == 0) out[0] = tot / (float)B;
    }
}

extern "C" void kernel_launch(void* const* d_in, const int* in_sizes, int n_in,
                              void* d_out, int out_size, void* d_ws, size_t ws_size,
                              hipStream_t stream) {
    const float* p = (const float*)d_in[0];
    const float* q = (const float*)d_in[1];
    const int*   r = (const int*)d_in[2];
    float* out     = (float*)d_out;

    float* partial     = (float*)d_ws;
    unsigned int* flag = (unsigned int*)((char*)d_ws + NBLOCKS * sizeof(float));

    const int B = in_sizes[0] / C;

    int nblocks = NBLOCKS;
    const size_t need = (size_t)NBLOCKS * sizeof(float) + sizeof(unsigned int);
    if (ws_size < need) {
        nblocks = (int)((ws_size - sizeof(unsigned int)) / sizeof(float));
        if (nblocks < 1) nblocks = 1;
        flag = (unsigned int*)((char*)d_ws + nblocks * sizeof(float));
    }

    hipMemsetAsync(flag, 0, sizeof(unsigned int), stream);
    emd_fused<<<nblocks, BLOCK, 0, stream>>>(p, q, r, partial, flag, out, B);
}

// Round 4
// 32.653 us; speedup vs baseline: 3.0894x; 1.4599x over previous
//
#include <hip/hip_runtime.h>
#include <math.h>

// Loss_58317065945194: per-sample EMD over C=10 bins, averaged over B samples.
//   diff = p - q               [B, C]
//   cdf  = cumsum(diff, axis=1)
//   per_sample = (mean_c |cdf|^r)^(1/r)
//   out = mean_b per_sample
//
// R4: two-kernel structure (fusion regressed twice: threadfence +68us,
// agent-atomics +15us). Main kernel now loads PERFECTLY COALESCED
// (lane -> consecutive float4) and stages tiles through LDS; each thread
// reads its 2-sample pair (80 B) back from LDS. Stride-80 ds_read_b128
// windows tile the 32 banks exactly -> conflict-spread.
// Tests whether R1's 80B-strided global pattern (not HBM BW) was the limiter
// (inputs are L3-resident: 168 MB < 256 MB Infinity Cache).

constexpr int C = 10;
constexpr int BLOCK = 256;
constexpr int TILE = 256;               // pairs staged per block-tile
constexpr int F4T = TILE * 5;           // float4 per array per tile (1280)
constexpr int NBLOCKS = 1024;           // 40 KB LDS/block -> 4 blocks/CU, all co-resident

__device__ __forceinline__ float block_reduce_sum(float v) {
    #pragma unroll
    for (int off = 32; off > 0; off >>= 1)
        v += __shfl_down(v, off, 64);
    __shared__ float smem[BLOCK / 64];
    const int lane = threadIdx.x & 63;
    const int wid  = threadIdx.x >> 6;
    if (lane == 0) smem[wid] = v;
    __syncthreads();
    float s = 0.0f;
    if (threadIdx.x == 0) {
        #pragma unroll
        for (int w = 0; w < BLOCK / 64; ++w) s += smem[w];
    }
    return s;  // valid in thread 0 only
}

// per-pair math: d[20] -> sum of two per-sample EMD values
__device__ __forceinline__ float pair_emd(const float* d, int r) {
    float res = 0.0f;
    if (r == 2) {
        #pragma unroll
        for (int s = 0; s < 2; ++s) {
            float cum = 0.0f, acc = 0.0f;
            #pragma unroll
            for (int c = 0; c < C; ++c) {
                cum += d[s * C + c];
                acc += cum * cum;
            }
            res += sqrtf(acc * (1.0f / C));
        }
    } else {
        const float rf = (float)r, rinv = 1.0f / rf;
        #pragma unroll
        for (int s = 0; s < 2; ++s) {
            float cum = 0.0f, acc = 0.0f;
            #pragma unroll
            for (int c = 0; c < C; ++c) {
                cum += d[s * C + c];
                acc += powf(fabsf(cum), rf);
            }
            res += powf(acc * (1.0f / C), rinv);
        }
    }
    return res;
}

__global__ __launch_bounds__(BLOCK) void emd_partial(
    const float* __restrict__ p, const float* __restrict__ q,
    const int* __restrict__ rptr, float* __restrict__ partial, int B)
{
    __shared__ float4 sp[F4T];   // 20 KB
    __shared__ float4 sq[F4T];   // 20 KB

    const int tid = threadIdx.x;
    const int r   = rptr[0];
    const int npairs = B >> 1;
    const int ntiles = npairs / TILE;          // full tiles
    const int rem    = npairs - ntiles * TILE; // tail pairs (0 for B=2M)

    const float4* p4 = reinterpret_cast<const float4*>(p);
    const float4* q4 = reinterpret_cast<const float4*>(q);

    float local = 0.0f;

    for (int t = blockIdx.x; t < ntiles; t += gridDim.x) {
        const size_t base = (size_t)t * F4T;   // tile base in float4 units

        // stage: fully coalesced (lane i -> consecutive float4)
        float4 rp[5], rq[5];
        #pragma unroll
        for (int k = 0; k < 5; ++k) {
            rp[k] = p4[base + tid + BLOCK * k];
            rq[k] = q4[base + tid + BLOCK * k];
        }
        #pragma unroll
        for (int k = 0; k < 5; ++k) {
            sp[tid + BLOCK * k] = rp[k];
            sq[tid + BLOCK * k] = rq[k];
        }
        __syncthreads();

        // consume: this thread's pair = 5 consecutive float4 (80 B stride)
        const float4* spp = &sp[tid * 5];
        const float4* sqq = &sq[tid * 5];
        float d[2 * C];
        #pragma unroll
        for (int j = 0; j < 5; ++j) {
            float4 a = spp[j];
            float4 b = sqq[j];
            d[4*j+0] = a.x - b.x;
            d[4*j+1] = a.y - b.y;
            d[4*j+2] = a.z - b.z;
            d[4*j+3] = a.w - b.w;
        }
        local += pair_emd(d, r);
        __syncthreads();   // protect LDS before next stage
    }

    // tail pairs (strided loads, tiny count), block 0 only
    if (rem && blockIdx.x == 0 && tid < rem) {
        const size_t pi = (size_t)ntiles * TILE + tid;
        float d[2 * C];
        #pragma unroll
        for (int k = 0; k < 5; ++k) {
            float4 a = p4[pi * 5 + k];
            float4 b = q4[pi * 5 + k];
            d[4*k+0] = a.x - b.x;
            d[4*k+1] = a.y - b.y;
            d[4*k+2] = a.z - b.z;
            d[4*k+3] = a.w - b.w;
        }
        local += pair_emd(d, r);
    }

    // odd-B tail sample
    if ((B & 1) && blockIdx.x == 0 && tid == 0) {
        const size_t base = (size_t)(B - 1) * C;
        float cum = 0.0f, acc = 0.0f;
        for (int c = 0; c < C; ++c) {
            cum += p[base + c] - q[base + c];
            acc += (r == 2) ? cum * cum : powf(fabsf(cum), (float)r);
        }
        local += (r == 2) ? sqrtf(acc * (1.0f / C))
                          : powf(acc * (1.0f / C), 1.0f / (float)r);
    }

    float s = block_reduce_sum(local);
    if (tid == 0) partial[blockIdx.x] = s;
}

__global__ __launch_bounds__(BLOCK) void emd_reduce(
    const float* __restrict__ partial, int n, float* __restrict__ out, float invB)
{
    float local = 0.0f;
    for (int i = threadIdx.x; i < n; i += BLOCK) local += partial[i];
    float s = block_reduce_sum(local);
    if (threadIdx.x == 0) out[0] = s * invB;
}

extern "C" void kernel_launch(void* const* d_in, const int* in_sizes, int n_in,
                              void* d_out, int out_size, void* d_ws, size_t ws_size,
                              hipStream_t stream) {
    const float* p = (const float*)d_in[0];
    const float* q = (const float*)d_in[1];
    const int*   r = (const int*)d_in[2];
    float* out     = (float*)d_out;
    float* partial = (float*)d_ws;

    const int B = in_sizes[0] / C;

    int nblocks = NBLOCKS;
    const int max_ws_blocks = (int)(ws_size / sizeof(float));
    if (nblocks > max_ws_blocks) nblocks = max_ws_blocks;
    if (nblocks < 1) nblocks = 1;

    emd_partial<<<nblocks, BLOCK, 0, stream>>>(p, q, r, partial, B);
    emd_reduce<<<1, BLOCK, 0, stream>>>(partial, nblocks, out, 1.0f / (float)B);
}